// Round 11
// baseline (189.185 us; speedup 1.0000x reference)
//
#include <hip/hip_runtime.h>
#include <math.h>

#define NN 8192

typedef __attribute__((ext_vector_type(8))) short short8;
typedef __attribute__((ext_vector_type(4))) short short4v;
typedef __attribute__((ext_vector_type(4))) float f32x4;

#define L2E 1.4426950408889634f

__device__ __forceinline__ short f2bf(float f) {
    union { float f; unsigned u; } v; v.f = f;
    unsigned r = v.u + 0x7fffu + ((v.u >> 16) & 1u);
    return (short)(r >> 16);
}

__device__ __forceinline__ f32x4 zero4() {
    f32x4 v; v[0] = 0.f; v[1] = 0.f; v[2] = 0.f; v[3] = 0.f; return v;
}

// ---------- K0: WT[f][k] = bf16(W[k][f]) ----------
__global__ void k0_wt(const float* __restrict__ W, short* __restrict__ WT) {
    int idx = blockIdx.x * 256 + threadIdx.x;
    if (idx < 256 * 128) {
        int k = idx & 255;
        int f = idx >> 8;
        WT[f * 256 + k] = f2bf(W[k * 128 + f]);
    }
}

// ---------- K_pack: bitmask[m] = ballot over 64 adj entries ----------
// Pure streaming: per wave-iter one coalesced 256B read + ballot + 8B store.
// word m covers flat adj[m*64 .. m*64+63]; bit l = (adj[m*64+l] > 0).
// Row-major: row r, col c -> word r*128 + c/64, bit c%64.
__global__ __launch_bounds__(256) void k_pack(
        const int* __restrict__ adj, unsigned long long* __restrict__ bm) {
    const int l = threadIdx.x & 63;
    const size_t wid = (size_t)blockIdx.x * 4 + (threadIdx.x >> 6);
    const size_t nw = (size_t)gridDim.x * 4;
    const size_t NWORDS = (size_t)NN * NN / 64;
    for (size_t m = wid; m < NWORDS; m += nw) {
        const int v = adj[m * 64 + l];
        const unsigned long long mask = __ballot(v > 0);
        if (l == 0) bm[m] = mask;
    }
}

// ---------- K1: h = x@W (bf16 MFMA); s1L2E/s2L2E; hT bf16 [128][8192] ----------
__global__ __launch_bounds__(128) void k1_h(
        const float* __restrict__ x, const short* __restrict__ WT,
        const float* __restrict__ a, short* __restrict__ hT,
        float* __restrict__ s1L2E, float* __restrict__ s2L2E) {
    const int w = threadIdx.x >> 6;
    const int l = threadIdx.x & 63;
    const int quad = l >> 4;
    const int fr = l & 15;
    const int i0 = blockIdx.x * 32 + w * 16;

    f32x4 acc[8];
#pragma unroll
    for (int t = 0; t < 8; ++t) acc[t] = zero4();

    const float* xrow = x + (size_t)(i0 + fr) * 256;
#pragma unroll
    for (int kk = 0; kk < 8; ++kk) {
        const int k0 = kk * 32 + quad * 8;
        f32x4 xa = *(const f32x4*)(xrow + k0);
        f32x4 xb = *(const f32x4*)(xrow + k0 + 4);
        short8 av;
#pragma unroll
        for (int e = 0; e < 4; ++e) { av[e] = f2bf(xa[e]); av[4 + e] = f2bf(xb[e]); }
#pragma unroll
        for (int t = 0; t < 8; ++t) {
            short8 bv = *(const short8*)(WT + (t * 16 + fr) * 256 + k0);
            acc[t] = __builtin_amdgcn_mfma_f32_16x16x32_bf16(av, bv, acc[t], 0, 0, 0);
        }
    }

    float s1p[4] = {0.f, 0.f, 0.f, 0.f};
    float s2p[4] = {0.f, 0.f, 0.f, 0.f};
#pragma unroll
    for (int t = 0; t < 8; ++t) {
        float a1v = a[t * 16 + fr];
        float a2v = a[128 + t * 16 + fr];
#pragma unroll
        for (int r = 0; r < 4; ++r) {
            s1p[r] += acc[t][r] * a1v;
            s2p[r] += acc[t][r] * a2v;
        }
    }
#pragma unroll
    for (int r = 0; r < 4; ++r) {
#pragma unroll
        for (int m = 1; m < 16; m <<= 1) {
            s1p[r] += __shfl_xor(s1p[r], m, 64);
            s2p[r] += __shfl_xor(s2p[r], m, 64);
        }
    }
    if (fr == 0) {
#pragma unroll
        for (int r = 0; r < 4; ++r) {
            const int i = i0 + quad * 4 + r;
            s1L2E[i] = s1p[r] * L2E;
            s2L2E[i] = s2p[r] * L2E;
        }
    }

#pragma unroll
    for (int t = 0; t < 8; ++t) {
        short4v hv;
#pragma unroll
        for (int r = 0; r < 4; ++r) hv[r] = f2bf(acc[t][r]);
        *(short4v*)(hT + (size_t)(t * 16 + fr) * NN + i0 + quad * 4) = hv;
    }
}

// ---------- K2: bitmask-driven masked-softmax + PV, all-L2 data ----------
// Block: 32 rows x JW cols; 4 waves = disjoint 32-col strips of each 128-col
// step, each wave covers all 32 rows (2 M-tiles, acc[2][8]).
// ALL inputs L2/L3-resident (bm 8MB, hT 2MB, s2 32KB) -> plain loads, no
// staging, no barriers, no asm, compiler-inserted waits; TLP (3 blocks/CU,
// 12 waves) hides L2 latency. (R9/R10 lesson: hand-counted vmcnt over mixed
// load types is unsound under possible spills -- eliminated entirely.)
template<int JSPLIT, bool PARTIAL>
__global__ __launch_bounds__(256, 3) void k2_attn(
        const unsigned long long* __restrict__ bm, const short* __restrict__ hT,
        const float* __restrict__ s1g, const float* __restrict__ s2g,
        float* __restrict__ pvp, float* __restrict__ zp,
        float* __restrict__ out) {
    constexpr int JW = NN / JSPLIT;
    constexpr int NSTEP = JW / 128;
    __shared__ __align__(16) char lds_c[16384 + 512];   // epilogue only

    const int tid = threadIdx.x;
    const int w = tid >> 6;
    const int l = tid & 63;
    const int quad = l >> 4;
    const int fr = l & 15;
    const int r32 = (blockIdx.x / JSPLIT) * 32;
    const int jb = blockIdx.x % JSPLIT;
    const int jbb = jb * JW;

    const float S0 = s1g[r32 + fr];        // rows 0..15  (M-tile 0)
    const float S1 = s1g[r32 + 16 + fr];   // rows 16..31 (M-tile 1)

    // bitmask words: row r, step t -> word r*128 + jbb/64 + t*2 + (w>>1);
    // lane's 8 cols are bits [(w&1)*32 + quad*8, +8).
    const unsigned long long* bw0 = bm + (size_t)(r32 + fr) * (NN / 64)
                                  + (jbb / 64) + (w >> 1);
    const unsigned long long* bw1 = bw0 + (size_t)16 * (NN / 64);
    const int bsh = (w & 1) * 32 + quad * 8;

    const short* hbase = hT + (size_t)fr * NN + jbb + w * 32 + quad * 8;
    const float* cbase = s2g + jbb + w * 32 + quad * 8;

    f32x4 acc[2][8];
#pragma unroll
    for (int m = 0; m < 2; ++m)
#pragma unroll
        for (int t = 0; t < 8; ++t) acc[m][t] = zero4();
    float zacc0 = 0.f, zacc1 = 0.f;

    for (int t = 0; t < NSTEP; ++t) {
        const int jo = t * 128;

        const unsigned long long b0 = bw0[t * 2];
        const unsigned long long b1 = bw1[t * 2];
        const f32x4 c0 = *(const f32x4*)(cbase + jo);
        const f32x4 c1 = *(const f32x4*)(cbase + jo + 4);
        short8 bv[8];
#pragma unroll
        for (int F = 0; F < 8; ++F)
            bv[F] = *(const short8*)(hbase + (size_t)F * 16 * NN + jo);

        const unsigned bb0 = (unsigned)(b0 >> bsh) & 0xffu;
        const unsigned bb1 = (unsigned)(b1 >> bsh) & 0xffu;

        short8 pa0, pa1;
        {
            float zs0 = 0.f, zs1 = 0.f;
#pragma unroll
            for (int e = 0; e < 8; ++e) {
                const float cv = (e < 4) ? c0[e] : c1[e - 4];
                const float u0 = S0 + cv;
                const float u1 = S1 + cv;
                const float t0 = fmaxf(u0, 0.2f * u0);
                const float t1 = fmaxf(u1, 0.2f * u1);
                const float p0 = ((bb0 >> e) & 1u) ? exp2f(t0) : 0.f;
                const float p1 = ((bb1 >> e) & 1u) ? exp2f(t1) : 0.f;
                zs0 += p0; zs1 += p1;
                pa0[e] = f2bf(p0);
                pa1[e] = f2bf(p1);
            }
            zacc0 += zs0; zacc1 += zs1;
        }

#pragma unroll
        for (int F = 0; F < 8; ++F) {
            acc[0][F] = __builtin_amdgcn_mfma_f32_16x16x32_bf16(pa0, bv[F], acc[0][F], 0, 0, 0);
            acc[1][F] = __builtin_amdgcn_mfma_f32_16x16x32_bf16(pa1, bv[F], acc[1][F], 0, 0, 0);
        }
    }

    // ---- epilogue: cross-wave reduction (single 16KB region, sequential) ----
    zacc0 += __shfl_xor(zacc0, 16, 64);
    zacc0 += __shfl_xor(zacc0, 32, 64);
    zacc1 += __shfl_xor(zacc1, 16, 64);
    zacc1 += __shfl_xor(zacc1, 32, 64);
    float* red = (float*)lds_c;
    float* zb = (float*)(lds_c + 16384);
    if (l < 16) {
        zb[w * 32 + l] = zacc0;
        zb[w * 32 + 16 + l] = zacc1;
    }

#pragma unroll
    for (int ww = 1; ww < 4; ++ww) {
        if (w == ww) {
#pragma unroll
            for (int m = 0; m < 2; ++m)
#pragma unroll
                for (int t = 0; t < 8; ++t)
                    *(f32x4*)(red + ((m * 8 + t) * 64 + l) * 4) = acc[m][t];
        }
        __syncthreads();
        if (w == 0) {
#pragma unroll
            for (int m = 0; m < 2; ++m)
#pragma unroll
                for (int t = 0; t < 8; ++t)
                    acc[m][t] += *(const f32x4*)(red + ((m * 8 + t) * 64 + l) * 4);
        }
        __syncthreads();
    }

    if (w == 0) {
#pragma unroll
        for (int m = 0; m < 2; ++m) {
#pragma unroll
            for (int r = 0; r < 4; ++r) {
                const int irow = m * 16 + quad * 4 + r;
                float z = 0.f;
#pragma unroll
                for (int ww = 0; ww < 4; ++ww) z += zb[ww * 32 + irow];
                const int grow = r32 + irow;
                if (PARTIAL) {
                    if (fr == 0) zp[(size_t)jb * NN + grow] = z;
                    float* orow = pvp + ((size_t)jb * NN + grow) * 128;
#pragma unroll
                    for (int t = 0; t < 8; ++t) orow[t * 16 + fr] = acc[m][t][r];
                } else {
                    const float inv = 1.0f / z;
                    float* orow = out + (size_t)grow * 128;
#pragma unroll
                    for (int t = 0; t < 8; ++t) {
                        float v = acc[m][t][r] * inv;
                        orow[t * 16 + fr] = (v > 0.f) ? v : expm1f(v);
                    }
                }
            }
        }
    }
}

// ---------- K3: sum partials, divide by Z, ELU ----------
__global__ __launch_bounds__(256) void k3_fin(
        const float* __restrict__ pvp, const float* __restrict__ zp,
        float* __restrict__ out, int jsplit) {
    const int idx = blockIdx.x * 256 + threadIdx.x;
    const int row = idx >> 5;
    const int c = (idx & 31) << 2;
    f32x4 s = zero4();
    float z = 0.f;
    for (int p = 0; p < jsplit; ++p) {
        s += *(const f32x4*)(pvp + ((size_t)p * NN + row) * 128 + c);
        z += zp[(size_t)p * NN + row];
    }
    const float inv = 1.0f / z;
    f32x4 o;
#pragma unroll
    for (int e = 0; e < 4; ++e) {
        float v = s[e] * inv;
        o[e] = (v > 0.f) ? v : expm1f(v);
    }
    *(f32x4*)(out + (size_t)row * 128 + c) = o;
}

extern "C" void kernel_launch(void* const* d_in, const int* in_sizes, int n_in,
                              void* d_out, int out_size, void* d_ws, size_t ws_size,
                              hipStream_t stream) {
    const float* x   = (const float*)d_in[0];   // 8192 x 256
    const float* W   = (const float*)d_in[1];   // 256 x 128
    const float* a   = (const float*)d_in[2];   // 256
    const int*   adj = (const int*)d_in[3];     // 8192 x 8192
    float* out = (float*)d_out;                 // 8192 x 128

    char* ws = (char*)d_ws;
    const size_t MB = 1024 * 1024;
    short* hT    = (short*)ws;                        // 2 MB
    float* s1L2E = (float*)(ws + 2 * MB);             // 32 KB
    float* s2L2E = (float*)(ws + 2 * MB + 32768);     // 32 KB
    short* WT    = (short*)(ws + 2 * MB + 65536);     // 64 KB
    unsigned long long* bmp = (unsigned long long*)(ws + 2 * MB + 131072);  // 8 MB
    const size_t base = 2 * MB + 131072 + (size_t)NN * NN / 8;

    auto need = [&](size_t js) {
        return base + js * ((size_t)NN * 128 * 4) + js * ((size_t)NN * 4);
    };
    int jsplit;
    if (ws_size >= need(4)) jsplit = 4;
    else if (ws_size >= need(2)) jsplit = 2;
    else if (ws_size >= need(1)) jsplit = 1;
    else jsplit = 0;

    float* pvp = (float*)(ws + base);
    float* zp  = (float*)(ws + base + (size_t)(jsplit > 0 ? jsplit : 1) * NN * 128 * 4);

    k0_wt<<<128, 256, 0, stream>>>(W, WT);
    k1_h<<<256, 128, 0, stream>>>(x, WT, a, hT, s1L2E, s2L2E);
    k_pack<<<2048, 256, 0, stream>>>(adj, bmp);

    if (jsplit == 4) {
        k2_attn<4, true><<<1024, 256, 0, stream>>>(bmp, hT, s1L2E, s2L2E, pvp, zp, nullptr);
        k3_fin<<<1024, 256, 0, stream>>>(pvp, zp, out, 4);
    } else if (jsplit == 2) {
        k2_attn<2, true><<<512, 256, 0, stream>>>(bmp, hT, s1L2E, s2L2E, pvp, zp, nullptr);
        k3_fin<<<1024, 256, 0, stream>>>(pvp, zp, out, 2);
    } else if (jsplit == 1) {
        k2_attn<1, true><<<256, 256, 0, stream>>>(bmp, hT, s1L2E, s2L2E, pvp, zp, nullptr);
        k3_fin<<<1024, 256, 0, stream>>>(pvp, zp, out, 1);
    } else {
        k2_attn<1, false><<<256, 256, 0, stream>>>(bmp, hT, s1L2E, s2L2E, nullptr, nullptr, out);
    }
}

// Round 12
// 122.205 us; speedup vs baseline: 1.5481x; 1.5481x over previous
//
#include <hip/hip_runtime.h>
#include <math.h>

#define NN 8192

typedef __attribute__((ext_vector_type(8))) short short8;
typedef __attribute__((ext_vector_type(4))) short short4v;
typedef __attribute__((ext_vector_type(4))) float f32x4;
typedef __attribute__((ext_vector_type(4))) int int4v;

#define L2E 1.4426950408889634f

typedef __attribute__((address_space(3))) unsigned lds_u32;
typedef __attribute__((address_space(1))) unsigned g_u32;

__device__ __forceinline__ void gll16(const void* g, void* l) {
    __builtin_amdgcn_global_load_lds((const g_u32*)g, (lds_u32*)l, 16, 0, 0);
}

__device__ __forceinline__ short f2bf(float f) {
    union { float f; unsigned u; } v; v.f = f;
    unsigned r = v.u + 0x7fffu + ((v.u >> 16) & 1u);
    return (short)(r >> 16);
}

__device__ __forceinline__ f32x4 zero4() {
    f32x4 v; v[0] = 0.f; v[1] = 0.f; v[2] = 0.f; v[3] = 0.f; return v;
}

// ---------- K0: WT[f][k] = bf16(W[k][f]) ----------
__global__ void k0_wt(const float* __restrict__ W, short* __restrict__ WT) {
    int idx = blockIdx.x * 256 + threadIdx.x;
    if (idx < 256 * 128) {
        int k = idx & 255;
        int f = idx >> 8;
        WT[f * 256 + k] = f2bf(W[k * 128 + f]);
    }
}

// ---------- K1: h = x@W (bf16 MFMA); s1L2E/s2L2E; hT bf16 [128][8192] ----------
__global__ __launch_bounds__(128) void k1_h(
        const float* __restrict__ x, const short* __restrict__ WT,
        const float* __restrict__ a, short* __restrict__ hT,
        float* __restrict__ s1L2E, float* __restrict__ s2L2E) {
    const int w = threadIdx.x >> 6;
    const int l = threadIdx.x & 63;
    const int quad = l >> 4;
    const int fr = l & 15;
    const int i0 = blockIdx.x * 32 + w * 16;

    f32x4 acc[8];
#pragma unroll
    for (int t = 0; t < 8; ++t) acc[t] = zero4();

    const float* xrow = x + (size_t)(i0 + fr) * 256;
#pragma unroll
    for (int kk = 0; kk < 8; ++kk) {
        const int k0 = kk * 32 + quad * 8;
        f32x4 xa = *(const f32x4*)(xrow + k0);
        f32x4 xb = *(const f32x4*)(xrow + k0 + 4);
        short8 av;
#pragma unroll
        for (int e = 0; e < 4; ++e) { av[e] = f2bf(xa[e]); av[4 + e] = f2bf(xb[e]); }
#pragma unroll
        for (int t = 0; t < 8; ++t) {
            short8 bv = *(const short8*)(WT + (t * 16 + fr) * 256 + k0);
            acc[t] = __builtin_amdgcn_mfma_f32_16x16x32_bf16(av, bv, acc[t], 0, 0, 0);
        }
    }

    float s1p[4] = {0.f, 0.f, 0.f, 0.f};
    float s2p[4] = {0.f, 0.f, 0.f, 0.f};
#pragma unroll
    for (int t = 0; t < 8; ++t) {
        float a1v = a[t * 16 + fr];
        float a2v = a[128 + t * 16 + fr];
#pragma unroll
        for (int r = 0; r < 4; ++r) {
            s1p[r] += acc[t][r] * a1v;
            s2p[r] += acc[t][r] * a2v;
        }
    }
#pragma unroll
    for (int r = 0; r < 4; ++r) {
#pragma unroll
        for (int m = 1; m < 16; m <<= 1) {
            s1p[r] += __shfl_xor(s1p[r], m, 64);
            s2p[r] += __shfl_xor(s2p[r], m, 64);
        }
    }
    if (fr == 0) {
#pragma unroll
        for (int r = 0; r < 4; ++r) {
            const int i = i0 + quad * 4 + r;
            s1L2E[i] = s1p[r] * L2E;
            s2L2E[i] = s2p[r] * L2E;
        }
    }

#pragma unroll
    for (int t = 0; t < 8; ++t) {
        short4v hv;
#pragma unroll
        for (int r = 0; r < 4; ++r) hv[r] = f2bf(acc[t][r]);
        *(short4v*)(hT + (size_t)(t * 16 + fr) * NN + i0 + quad * 4) = hv;
    }
}

// ---------- K2: fused pack + masked-softmax + PV ----------
// Block: 32 rows x JW cols, 4 waves (2 row-halves x 2 j-halves), 3 blocks/CU.
// Phase A: pack this block's adj tile -> LDS nibble bitmap (16KB). Each wave
//   streams its 8 rows as CONTIGUOUS 1KB wave-loads, 8 independent loads in
//   flight (fixes R6's 256B-chunk DRAM granularity AND R7/R11's ILP collapse).
//   adj read once, coalesced, then dead.
// Phase B: R6-verbatim hT gll staging (dbuf, XOR swizzle) + bm bits from LDS
//   + exp2-lrelu P + 8 MFMA/wave; ONE __syncthreads per step (R5-verified
//   control flow). Zero hand-counted vmcnt (R9/R10 failure class eliminated).
// LDS: [0,16K) bmB | [16K,48K) hT dbuf | [48K,50K) c dbuf | [50.25K] zbuf.
template<int JSPLIT, bool PARTIAL>
__global__ __launch_bounds__(256, 3) void k2_attn(
        const int* __restrict__ adj, const short* __restrict__ hT,
        const float* __restrict__ s1g, const float* __restrict__ s2g,
        float* __restrict__ pvp, float* __restrict__ zp,
        float* __restrict__ out) {
    constexpr int JW = NN / JSPLIT;
    constexpr int NSTEP = JW / 64;
    constexpr int NCH = JW / 256;
    __shared__ __align__(16) char lds_c[51456];

    const int tid = threadIdx.x;
    const int w = tid >> 6;
    const int l = tid & 63;
    const int quad = l >> 4;
    const int fr = l & 15;
    const int rh = w >> 1;
    const int wj = w & 1;
    const int rb = blockIdx.x / JSPLIT;
    const int jb = blockIdx.x % JSPLIT;
    const int r32 = rb * 32;
    const int jbb = jb * JW;

    const float S = s1g[r32 + rh * 16 + fr];   // s1*log2e, this lane's row

    // ---- hT gll sources (R6-verified: pre-swizzled, linear LDS dest) ----
    const char* hsrc[4];
    {
        const char* hbase = (const char*)hT;
#pragma unroll
        for (int p = 0; p < 4; ++p) {
            const int o = p * 4096 + tid * 16;
            const int row = o >> 7;                   // feature row (128B/row)
            const int colb = o & 127;
            hsrc[p] = hbase + (size_t)row * (NN * 2) + (size_t)jbb * 2
                    + (colb ^ ((row & 7) << 4));
        }
    }
    const char* csrc = (const char*)s2g + (size_t)jbb * 4 + l * 16;

    auto STAGE = [&](int jt, int buf) {
        char* hd = lds_c + 16384 + buf * 16384 + w * 1024;
        char* cd = lds_c + 49152 + buf * 1024;
        const size_t hof = (size_t)jt * 128;
#pragma unroll
        for (int p = 0; p < 4; ++p) gll16(hsrc[p] + hof, hd + p * 4096);
        gll16(csrc + (size_t)jt * 256, cd);
    };

    // prologue stage rides under phase A
    STAGE(0, 0);

    // ---- Phase A: pack adj tile into LDS nibble bitmap ----
    // wave w owns rows w*8..w*8+7; per chunk c: 8 independent 1KB wave-loads.
    {
        const char* abase = (const char*)adj;
        for (int c = 0; c < NCH; ++c) {
            int4v v[8];
#pragma unroll
            for (int p = 0; p < 8; ++p) {
                const int r = w * 8 + p;
                v[p] = *(const int4v*)(abase + (size_t)(r32 + r) * (NN * 4)
                                     + (size_t)(jbb + c * 256) * 4 + l * 16);
            }
#pragma unroll
            for (int p = 0; p < 8; ++p) {
                const int r = w * 8 + p;
                const unsigned nib = (v[p][0] > 0 ? 1u : 0u) | (v[p][1] > 0 ? 2u : 0u)
                                   | (v[p][2] > 0 ? 4u : 0u) | (v[p][3] > 0 ? 8u : 0u);
                const int logical = c * 64 + l;       // byte covers cols logical*4..+3
                lds_c[r * 512 + (logical ^ ((r & 7) << 6))] = (char)nib;
            }
        }
    }
    __syncthreads();   // bmB complete + STAGE(0) drained

    f32x4 acc[8];
#pragma unroll
    for (int t = 0; t < 8; ++t) acc[t] = zero4();
    float zacc = 0.f;

    const int arow = rh * 16 + fr;
    const unsigned bswz = (unsigned)((arow & 7) << 6);

    int cur = 0;
    for (int t = 0; t < NSTEP; ++t) {
        if (t + 1 < NSTEP) STAGE(t + 1, cur ^ 1);
        __builtin_amdgcn_sched_barrier(0);

        const char* hb = lds_c + 16384 + cur * 16384;
        const float* cb = (const float*)(lds_c + 49152 + cur * 1024);

        // bm bits for this lane's row, 8 cols (u16 = 2 nibble-bytes)
        const unsigned blog = (unsigned)(t * 16 + wj * 8 + quad * 2);
        const unsigned bits = *(const unsigned short*)(lds_c + arow * 512 + (blog ^ bswz));

        const f32x4 c0 = *(const f32x4*)(cb + wj * 32 + quad * 8);
        const f32x4 c1 = *(const f32x4*)(cb + wj * 32 + quad * 8 + 4);

        short8 pa;
        {
            float zs = 0.f;
#pragma unroll
            for (int e = 0; e < 8; ++e) {
                const float cv = (e < 4) ? c0[e] : c1[e - 4];
                const unsigned bit = (bits >> ((e >> 2) * 8 + (e & 3))) & 1u;
                const float u = S + cv;                 // (s1+s2)*log2e
                const float tt = fmaxf(u, 0.2f * u);    // leaky-relu in log2 space
                const float p = bit ? exp2f(tt) : 0.f;
                zs += p;
                pa[e] = f2bf(p);
            }
            zacc += zs;
        }

#pragma unroll
        for (int t8 = 0; t8 < 8; ++t8) {
            const int hrow = t8 * 16 + fr;
            const short8 bv = *(const short8*)(
                hb + ((unsigned)(hrow * 128 + wj * 64 + quad * 16) ^ ((hrow & 7) << 4)));
            acc[t8] = __builtin_amdgcn_mfma_f32_16x16x32_bf16(pa, bv, acc[t8], 0, 0, 0);
        }

        __syncthreads();   // stage(t+1) drained; all waves done with buf cur
        cur ^= 1;
    }

    // ---- epilogue (R6-verified): red aliases hT buf0 ----
    zacc += __shfl_xor(zacc, 16, 64);
    zacc += __shfl_xor(zacc, 32, 64);
    float* zb = (float*)(lds_c + 51200);
    if (l < 16) zb[w * 16 + l] = zacc;

    float* red = (float*)(lds_c + 16384);
    if (wj == 1) {
#pragma unroll
        for (int t = 0; t < 8; ++t)
            *(f32x4*)(red + rh * 2048 + t * 256 + l * 4) = acc[t];
    }
    __syncthreads();

    if (wj == 0) {
#pragma unroll
        for (int t = 0; t < 8; ++t)
            acc[t] += *(const f32x4*)(red + rh * 2048 + t * 256 + l * 4);
#pragma unroll
        for (int r = 0; r < 4; ++r) {
            const int irow = quad * 4 + r;
            const float z = zb[rh * 32 + irow] + zb[rh * 32 + 16 + irow];
            const int grow = r32 + rh * 16 + irow;
            if (PARTIAL) {
                if (fr == 0) zp[(size_t)jb * NN + grow] = z;
                float* orow = pvp + ((size_t)jb * NN + grow) * 128;
#pragma unroll
                for (int t = 0; t < 8; ++t) orow[t * 16 + fr] = acc[t][r];
            } else {
                const float inv = 1.0f / z;
                float* orow = out + (size_t)grow * 128;
#pragma unroll
                for (int t = 0; t < 8; ++t) {
                    float v = acc[t][r] * inv;
                    orow[t * 16 + fr] = (v > 0.f) ? v : expm1f(v);
                }
            }
        }
    }
}

// ---------- K3: sum partials, divide by Z, ELU ----------
__global__ __launch_bounds__(256) void k3_fin(
        const float* __restrict__ pvp, const float* __restrict__ zp,
        float* __restrict__ out, int jsplit) {
    const int idx = blockIdx.x * 256 + threadIdx.x;
    const int row = idx >> 5;
    const int c = (idx & 31) << 2;
    f32x4 s = zero4();
    float z = 0.f;
    for (int p = 0; p < jsplit; ++p) {
        s += *(const f32x4*)(pvp + ((size_t)p * NN + row) * 128 + c);
        z += zp[(size_t)p * NN + row];
    }
    const float inv = 1.0f / z;
    f32x4 o;
#pragma unroll
    for (int e = 0; e < 4; ++e) {
        float v = s[e] * inv;
        o[e] = (v > 0.f) ? v : expm1f(v);
    }
    *(f32x4*)(out + (size_t)row * 128 + c) = o;
}

extern "C" void kernel_launch(void* const* d_in, const int* in_sizes, int n_in,
                              void* d_out, int out_size, void* d_ws, size_t ws_size,
                              hipStream_t stream) {
    const float* x   = (const float*)d_in[0];   // 8192 x 256
    const float* W   = (const float*)d_in[1];   // 256 x 128
    const float* a   = (const float*)d_in[2];   // 256
    const int*   adj = (const int*)d_in[3];     // 8192 x 8192
    float* out = (float*)d_out;                 // 8192 x 128

    char* ws = (char*)d_ws;
    const size_t MB = 1024 * 1024;
    short* hT    = (short*)ws;                        // 2 MB
    float* s1L2E = (float*)(ws + 2 * MB);             // 32 KB
    float* s2L2E = (float*)(ws + 2 * MB + 32768);     // 32 KB
    short* WT    = (short*)(ws + 2 * MB + 65536);     // 64 KB
    const size_t base = 2 * MB + 131072;

    auto need = [&](size_t js) {
        return base + js * ((size_t)NN * 128 * 4) + js * ((size_t)NN * 4);
    };
    int jsplit;
    if (ws_size >= need(4)) jsplit = 4;
    else if (ws_size >= need(2)) jsplit = 2;
    else if (ws_size >= need(1)) jsplit = 1;
    else jsplit = 0;

    float* pvp = (float*)(ws + base);
    float* zp  = (float*)(ws + base + (size_t)(jsplit > 0 ? jsplit : 1) * NN * 128 * 4);

    k0_wt<<<128, 256, 0, stream>>>(W, WT);
    k1_h<<<256, 128, 0, stream>>>(x, WT, a, hT, s1L2E, s2L2E);

    if (jsplit == 4) {
        k2_attn<4, true><<<1024, 256, 0, stream>>>(adj, hT, s1L2E, s2L2E, pvp, zp, nullptr);
        k3_fin<<<1024, 256, 0, stream>>>(pvp, zp, out, 4);
    } else if (jsplit == 2) {
        k2_attn<2, true><<<512, 256, 0, stream>>>(adj, hT, s1L2E, s2L2E, pvp, zp, nullptr);
        k3_fin<<<1024, 256, 0, stream>>>(pvp, zp, out, 2);
    } else if (jsplit == 1) {
        k2_attn<1, true><<<256, 256, 0, stream>>>(adj, hT, s1L2E, s2L2E, pvp, zp, nullptr);
        k3_fin<<<1024, 256, 0, stream>>>(pvp, zp, out, 1);
    } else {
        k2_attn<1, false><<<256, 256, 0, stream>>>(adj, hT, s1L2E, s2L2E, nullptr, nullptr, out);
    }
}

// Round 13
// 113.580 us; speedup vs baseline: 1.6657x; 1.0759x over previous
//
#include <hip/hip_runtime.h>
#include <math.h>

#define NN 8192

typedef __attribute__((ext_vector_type(8))) short short8;
typedef __attribute__((ext_vector_type(4))) short short4v;
typedef __attribute__((ext_vector_type(4))) float f32x4;
typedef __attribute__((ext_vector_type(4))) int int4v;

#define L2E 1.4426950408889634f

typedef __attribute__((address_space(3))) unsigned lds_u32;
typedef __attribute__((address_space(1))) unsigned g_u32;

__device__ __forceinline__ void gll16(const void* g, void* l) {
    __builtin_amdgcn_global_load_lds((const g_u32*)g, (lds_u32*)l, 16, 0, 0);
}

__device__ __forceinline__ short f2bf(float f) {
    union { float f; unsigned u; } v; v.f = f;
    unsigned r = v.u + 0x7fffu + ((v.u >> 16) & 1u);
    return (short)(r >> 16);
}

__device__ __forceinline__ f32x4 zero4() {
    f32x4 v; v[0] = 0.f; v[1] = 0.f; v[2] = 0.f; v[3] = 0.f; return v;
}

// ---------- K0: WT[f][k] = bf16(W[k][f]) ----------
__global__ void k0_wt(const float* __restrict__ W, short* __restrict__ WT) {
    int idx = blockIdx.x * 256 + threadIdx.x;
    if (idx < 256 * 128) {
        int k = idx & 255;
        int f = idx >> 8;
        WT[f * 256 + k] = f2bf(W[k * 128 + f]);
    }
}

// ---------- K1: h = x@W (bf16 MFMA); s1L2E/s2L2E; hT bf16 [128][8192] ----------
__global__ __launch_bounds__(128) void k1_h(
        const float* __restrict__ x, const short* __restrict__ WT,
        const float* __restrict__ a, short* __restrict__ hT,
        float* __restrict__ s1L2E, float* __restrict__ s2L2E) {
    const int w = threadIdx.x >> 6;
    const int l = threadIdx.x & 63;
    const int quad = l >> 4;
    const int fr = l & 15;
    const int i0 = blockIdx.x * 32 + w * 16;

    f32x4 acc[8];
#pragma unroll
    for (int t = 0; t < 8; ++t) acc[t] = zero4();

    const float* xrow = x + (size_t)(i0 + fr) * 256;
#pragma unroll
    for (int kk = 0; kk < 8; ++kk) {
        const int k0 = kk * 32 + quad * 8;
        f32x4 xa = *(const f32x4*)(xrow + k0);
        f32x4 xb = *(const f32x4*)(xrow + k0 + 4);
        short8 av;
#pragma unroll
        for (int e = 0; e < 4; ++e) { av[e] = f2bf(xa[e]); av[4 + e] = f2bf(xb[e]); }
#pragma unroll
        for (int t = 0; t < 8; ++t) {
            short8 bv = *(const short8*)(WT + (t * 16 + fr) * 256 + k0);
            acc[t] = __builtin_amdgcn_mfma_f32_16x16x32_bf16(av, bv, acc[t], 0, 0, 0);
        }
    }

    float s1p[4] = {0.f, 0.f, 0.f, 0.f};
    float s2p[4] = {0.f, 0.f, 0.f, 0.f};
#pragma unroll
    for (int t = 0; t < 8; ++t) {
        float a1v = a[t * 16 + fr];
        float a2v = a[128 + t * 16 + fr];
#pragma unroll
        for (int r = 0; r < 4; ++r) {
            s1p[r] += acc[t][r] * a1v;
            s2p[r] += acc[t][r] * a2v;
        }
    }
#pragma unroll
    for (int r = 0; r < 4; ++r) {
#pragma unroll
        for (int m = 1; m < 16; m <<= 1) {
            s1p[r] += __shfl_xor(s1p[r], m, 64);
            s2p[r] += __shfl_xor(s2p[r], m, 64);
        }
    }
    if (fr == 0) {
#pragma unroll
        for (int r = 0; r < 4; ++r) {
            const int i = i0 + quad * 4 + r;
            s1L2E[i] = s1p[r] * L2E;
            s2L2E[i] = s2p[r] * L2E;
        }
    }

#pragma unroll
    for (int t = 0; t < 8; ++t) {
        short4v hv;
#pragma unroll
        for (int r = 0; r < 4; ++r) hv[r] = f2bf(acc[t][r]);
        *(short4v*)(hT + (size_t)(t * 16 + fr) * NN + i0 + quad * 4) = hv;
    }
}

// ---------- K2: INTERLEAVED pack + masked-softmax + PV ----------
// R12 skeleton with phase A folded into the main loop (fixes the serial
// adj-burst): chunk c (256 cols x 32 rows, 8x1KB contiguous wave-loads)
// issues at step 4(c-2), nibble-packs into the LDS bitmap at step 4(c-2)+2;
// compute step t reads bitmap chunk t/4 (ready >=2 macros earlier). Pack
// loads are plain register loads (compiler waits -- no hand vmcnt). hT gll
// staging, XOR swizzles, per-step __syncthreads all R12-verified.
// JSPLIT=2: 512 blocks = exactly 2/CU, no ragged tail; k3 traffic halved.
// LDS: bitmap 32*BMB | hT dbuf 2x16K | c dbuf 2x1K | zbuf.
template<int JSPLIT, bool PARTIAL>
__global__ __launch_bounds__(256, 2) void k2_attn(
        const int* __restrict__ adj, const short* __restrict__ hT,
        const float* __restrict__ s1g, const float* __restrict__ s2g,
        float* __restrict__ pvp, float* __restrict__ zp,
        float* __restrict__ out) {
    constexpr int JW = NN / JSPLIT;
    constexpr int NSTEP = JW / 64;
    constexpr int NCH = JW / 256;
    constexpr int BMB = JW / 4;            // bitmap bytes per row
    constexpr int BMOFF = 32 * BMB;
    __shared__ __align__(16) char lds_c[BMOFF + 32768 + 2048 + 256];

    const int tid = threadIdx.x;
    const int w = tid >> 6;
    const int l = tid & 63;
    const int quad = l >> 4;
    const int fr = l & 15;
    const int rh = w >> 1;
    const int wj = w & 1;
    const int rb = blockIdx.x / JSPLIT;
    const int jb = blockIdx.x % JSPLIT;
    const int r32 = rb * 32;
    const int jbb = jb * JW;

    const float S = s1g[r32 + rh * 16 + fr];   // s1*log2e, this lane's row

    // ---- hT gll sources (pre-swizzled, linear LDS dest) ----
    const char* hsrc[4];
    {
        const char* hbase = (const char*)hT;
#pragma unroll
        for (int p = 0; p < 4; ++p) {
            const int o = p * 4096 + tid * 16;
            const int row = o >> 7;                   // feature row (128B/row)
            const int colb = o & 127;
            hsrc[p] = hbase + (size_t)row * (NN * 2) + (size_t)jbb * 2
                    + (colb ^ ((row & 7) << 4));
        }
    }
    const char* csrc = (const char*)s2g + (size_t)jbb * 4 + l * 16;

    auto STAGE = [&](int jt, int buf) {
        char* hd = lds_c + BMOFF + buf * 16384 + w * 1024;
        char* cd = lds_c + BMOFF + 32768 + buf * 1024;
        const size_t hof = (size_t)jt * 128;
#pragma unroll
        for (int p = 0; p < 4; ++p) gll16(hsrc[p] + hof, hd + p * 4096);
        gll16(csrc + (size_t)jt * 256, cd);
    };

    // ---- interleaved pack machinery (wave w owns rows w*8..w*8+7) ----
    const char* abase = (const char*)adj;
    int4v pv[8];
    auto PACK_LOAD = [&](int c) {
#pragma unroll
        for (int p = 0; p < 8; ++p) {
            const int r = w * 8 + p;
            pv[p] = *(const int4v*)(abase + (size_t)(r32 + r) * (NN * 4)
                                  + (size_t)(jbb + c * 256) * 4 + l * 16);
        }
    };
    auto PACK_PROC = [&](int c) {
#pragma unroll
        for (int p = 0; p < 8; ++p) {
            const int r = w * 8 + p;
            const unsigned nib = (pv[p][0] > 0 ? 1u : 0u) | (pv[p][1] > 0 ? 2u : 0u)
                               | (pv[p][2] > 0 ? 4u : 0u) | (pv[p][3] > 0 ? 8u : 0u);
            const int logical = c * 64 + l;           // byte covers cols logical*4..+3
            lds_c[r * BMB + (logical ^ ((r & 7) << 6))] = (char)nib;
        }
    };

    // prologue: stage(0) + pack chunks 0,1
    STAGE(0, 0);
    PACK_LOAD(0); PACK_PROC(0);
    PACK_LOAD(1); PACK_PROC(1);
    __syncthreads();   // bitmap chunks 0,1 + STAGE(0) visible

    f32x4 acc[8];
#pragma unroll
    for (int t = 0; t < 8; ++t) acc[t] = zero4();
    float zacc = 0.f;

    const int arow = rh * 16 + fr;
    const unsigned bswz = (unsigned)((arow & 7) << 6);

    int cur = 0;
    for (int t = 0; t < NSTEP; ++t) {
        if (t + 1 < NSTEP) STAGE(t + 1, cur ^ 1);
        {
            const int c2 = (t >> 2) + 2;
            if ((t & 3) == 0 && c2 < NCH) PACK_LOAD(c2);   // issue 2 macros early
            if ((t & 3) == 2 && c2 < NCH) PACK_PROC(c2);   // pack 1.5 macros early
        }
        __builtin_amdgcn_sched_barrier(0);

        const char* hb = lds_c + BMOFF + cur * 16384;
        const float* cb = (const float*)(lds_c + BMOFF + 32768 + cur * 1024);

        // bm bits for this lane's row, 8 cols (u16 = 2 nibble-bytes)
        const unsigned blog = (unsigned)(t * 16 + wj * 8 + quad * 2);
        const unsigned bits = *(const unsigned short*)(lds_c + arow * BMB + (blog ^ bswz));

        const f32x4 c0 = *(const f32x4*)(cb + wj * 32 + quad * 8);
        const f32x4 c1 = *(const f32x4*)(cb + wj * 32 + quad * 8 + 4);

        short8 pa;
        {
            float zs = 0.f;
#pragma unroll
            for (int e = 0; e < 8; ++e) {
                const float cv = (e < 4) ? c0[e] : c1[e - 4];
                const unsigned bit = (bits >> ((e >> 2) * 8 + (e & 3))) & 1u;
                const float u = S + cv;                 // (s1+s2)*log2e
                const float tt = fmaxf(u, 0.2f * u);    // leaky-relu in log2 space
                const float p = bit ? exp2f(tt) : 0.f;
                zs += p;
                pa[e] = f2bf(p);
            }
            zacc += zs;
        }

#pragma unroll
        for (int t8 = 0; t8 < 8; ++t8) {
            const int hrow = t8 * 16 + fr;
            const short8 bv = *(const short8*)(
                hb + ((unsigned)(hrow * 128 + wj * 64 + quad * 16) ^ ((hrow & 7) << 4)));
            acc[t8] = __builtin_amdgcn_mfma_f32_16x16x32_bf16(pa, bv, acc[t8], 0, 0, 0);
        }

        __syncthreads();   // stage(t+1)+pack writes drained; buf cur free
        cur ^= 1;
    }

    // ---- epilogue: red aliases hT dbuf; zbuf in its own slot ----
    zacc += __shfl_xor(zacc, 16, 64);
    zacc += __shfl_xor(zacc, 32, 64);
    float* zb = (float*)(lds_c + BMOFF + 32768 + 2048);
    if (l < 16) zb[w * 16 + l] = zacc;

    float* red = (float*)(lds_c + BMOFF);
    if (wj == 1) {
#pragma unroll
        for (int t = 0; t < 8; ++t)
            *(f32x4*)(red + rh * 2048 + t * 256 + l * 4) = acc[t];
    }
    __syncthreads();

    if (wj == 0) {
#pragma unroll
        for (int t = 0; t < 8; ++t)
            acc[t] += *(const f32x4*)(red + rh * 2048 + t * 256 + l * 4);
#pragma unroll
        for (int r = 0; r < 4; ++r) {
            const int irow = quad * 4 + r;
            const float z = zb[rh * 32 + irow] + zb[rh * 32 + 16 + irow];
            const int grow = r32 + rh * 16 + irow;
            if (PARTIAL) {
                if (fr == 0) zp[(size_t)jb * NN + grow] = z;
                float* orow = pvp + ((size_t)jb * NN + grow) * 128;
#pragma unroll
                for (int t = 0; t < 8; ++t) orow[t * 16 + fr] = acc[t][r];
            } else {
                const float inv = 1.0f / z;
                float* orow = out + (size_t)grow * 128;
#pragma unroll
                for (int t = 0; t < 8; ++t) {
                    float v = acc[t][r] * inv;
                    orow[t * 16 + fr] = (v > 0.f) ? v : expm1f(v);
                }
            }
        }
    }
}

// ---------- K3: sum partials, divide by Z, ELU ----------
__global__ __launch_bounds__(256) void k3_fin(
        const float* __restrict__ pvp, const float* __restrict__ zp,
        float* __restrict__ out, int jsplit) {
    const int idx = blockIdx.x * 256 + threadIdx.x;
    const int row = idx >> 5;
    const int c = (idx & 31) << 2;
    f32x4 s = zero4();
    float z = 0.f;
    for (int p = 0; p < jsplit; ++p) {
        s += *(const f32x4*)(pvp + ((size_t)p * NN + row) * 128 + c);
        z += zp[(size_t)p * NN + row];
    }
    const float inv = 1.0f / z;
    f32x4 o;
#pragma unroll
    for (int e = 0; e < 4; ++e) {
        float v = s[e] * inv;
        o[e] = (v > 0.f) ? v : expm1f(v);
    }
    *(f32x4*)(out + (size_t)row * 128 + c) = o;
}

extern "C" void kernel_launch(void* const* d_in, const int* in_sizes, int n_in,
                              void* d_out, int out_size, void* d_ws, size_t ws_size,
                              hipStream_t stream) {
    const float* x   = (const float*)d_in[0];   // 8192 x 256
    const float* W   = (const float*)d_in[1];   // 256 x 128
    const float* a   = (const float*)d_in[2];   // 256
    const int*   adj = (const int*)d_in[3];     // 8192 x 8192
    float* out = (float*)d_out;                 // 8192 x 128

    char* ws = (char*)d_ws;
    const size_t MB = 1024 * 1024;
    short* hT    = (short*)ws;                        // 2 MB
    float* s1L2E = (float*)(ws + 2 * MB);             // 32 KB
    float* s2L2E = (float*)(ws + 2 * MB + 32768);     // 32 KB
    short* WT    = (short*)(ws + 2 * MB + 65536);     // 64 KB
    const size_t base = 2 * MB + 131072;

    auto need = [&](size_t js) {
        return base + js * ((size_t)NN * 128 * 4) + js * ((size_t)NN * 4);
    };
    int jsplit;
    if (ws_size >= need(2)) jsplit = 2;
    else if (ws_size >= need(1)) jsplit = 1;
    else jsplit = 0;

    float* pvp = (float*)(ws + base);
    float* zp  = (float*)(ws + base + (size_t)(jsplit > 0 ? jsplit : 1) * NN * 128 * 4);

    k0_wt<<<128, 256, 0, stream>>>(W, WT);
    k1_h<<<256, 128, 0, stream>>>(x, WT, a, hT, s1L2E, s2L2E);

    if (jsplit == 2) {
        k2_attn<2, true><<<512, 256, 0, stream>>>(adj, hT, s1L2E, s2L2E, pvp, zp, nullptr);
        k3_fin<<<1024, 256, 0, stream>>>(pvp, zp, out, 2);
    } else if (jsplit == 1) {
        k2_attn<1, true><<<256, 256, 0, stream>>>(adj, hT, s1L2E, s2L2E, pvp, zp, nullptr);
        k3_fin<<<1024, 256, 0, stream>>>(pvp, zp, out, 1);
    } else {
        k2_attn<1, false><<<256, 256, 0, stream>>>(adj, hT, s1L2E, s2L2E, nullptr, nullptr, out);
    }
}

// Round 14
// 83.907 us; speedup vs baseline: 2.2547x; 1.3536x over previous
//
#include <hip/hip_runtime.h>
#include <math.h>

#define NN 8192

typedef __attribute__((ext_vector_type(8))) short short8;
typedef __attribute__((ext_vector_type(4))) short short4v;
typedef __attribute__((ext_vector_type(4))) float f32x4;
typedef __attribute__((ext_vector_type(4))) int int4v;

#define L2E 1.4426950408889634f

typedef __attribute__((address_space(3))) unsigned lds_u32;
typedef __attribute__((address_space(1))) unsigned g_u32;

__device__ __forceinline__ void gll16(const void* g, void* l) {
    __builtin_amdgcn_global_load_lds((const g_u32*)g, (lds_u32*)l, 16, 0, 0);
}

__device__ __forceinline__ short f2bf(float f) {
    union { float f; unsigned u; } v; v.f = f;
    unsigned r = v.u + 0x7fffu + ((v.u >> 16) & 1u);
    return (short)(r >> 16);
}

__device__ __forceinline__ f32x4 zero4() {
    f32x4 v; v[0] = 0.f; v[1] = 0.f; v[2] = 0.f; v[3] = 0.f; return v;
}

// ---------- K0: WT[f][k] = bf16(W[k][f]) ----------
__global__ void k0_wt(const float* __restrict__ W, short* __restrict__ WT) {
    int idx = blockIdx.x * 256 + threadIdx.x;
    if (idx < 256 * 128) {
        int k = idx & 255;
        int f = idx >> 8;
        WT[f * 256 + k] = f2bf(W[k * 128 + f]);
    }
}

// ---------- K1: h = x@W (bf16 MFMA); s1L2E/s2L2E; hT bf16 [128][8192] ----------
__global__ __launch_bounds__(128) void k1_h(
        const float* __restrict__ x, const short* __restrict__ WT,
        const float* __restrict__ a, short* __restrict__ hT,
        float* __restrict__ s1L2E, float* __restrict__ s2L2E) {
    const int w = threadIdx.x >> 6;
    const int l = threadIdx.x & 63;
    const int quad = l >> 4;
    const int fr = l & 15;
    const int i0 = blockIdx.x * 32 + w * 16;

    f32x4 acc[8];
#pragma unroll
    for (int t = 0; t < 8; ++t) acc[t] = zero4();

    const float* xrow = x + (size_t)(i0 + fr) * 256;
#pragma unroll
    for (int kk = 0; kk < 8; ++kk) {
        const int k0 = kk * 32 + quad * 8;
        f32x4 xa = *(const f32x4*)(xrow + k0);
        f32x4 xb = *(const f32x4*)(xrow + k0 + 4);
        short8 av;
#pragma unroll
        for (int e = 0; e < 4; ++e) { av[e] = f2bf(xa[e]); av[4 + e] = f2bf(xb[e]); }
#pragma unroll
        for (int t = 0; t < 8; ++t) {
            short8 bv = *(const short8*)(WT + (t * 16 + fr) * 256 + k0);
            acc[t] = __builtin_amdgcn_mfma_f32_16x16x32_bf16(av, bv, acc[t], 0, 0, 0);
        }
    }

    float s1p[4] = {0.f, 0.f, 0.f, 0.f};
    float s2p[4] = {0.f, 0.f, 0.f, 0.f};
#pragma unroll
    for (int t = 0; t < 8; ++t) {
        float a1v = a[t * 16 + fr];
        float a2v = a[128 + t * 16 + fr];
#pragma unroll
        for (int r = 0; r < 4; ++r) {
            s1p[r] += acc[t][r] * a1v;
            s2p[r] += acc[t][r] * a2v;
        }
    }
#pragma unroll
    for (int r = 0; r < 4; ++r) {
#pragma unroll
        for (int m = 1; m < 16; m <<= 1) {
            s1p[r] += __shfl_xor(s1p[r], m, 64);
            s2p[r] += __shfl_xor(s2p[r], m, 64);
        }
    }
    if (fr == 0) {
#pragma unroll
        for (int r = 0; r < 4; ++r) {
            const int i = i0 + quad * 4 + r;
            s1L2E[i] = s1p[r] * L2E;
            s2L2E[i] = s2p[r] * L2E;
        }
    }

#pragma unroll
    for (int t = 0; t < 8; ++t) {
        short4v hv;
#pragma unroll
        for (int r = 0; r < 4; ++r) hv[r] = f2bf(acc[t][r]);
        *(short4v*)(hT + (size_t)(t * 16 + fr) * NN + i0 + quad * 4) = hv;
    }
}

// ---------- K2: 64-row blocks, all-gll counted-vmcnt pipeline (R6 regime) ----------
// Block: 64 rows x JW(2048) cols; 4 waves = 2 rh x 2 wj; each wave owns
// 32 rows (2 M-tiles, acc[2][8]) x 32 cols/step; bv shared across M-tiles
// -> 16 MFMA per wave-step for the same staged bytes (2x R6's intensity).
// Per step (64 cols): stage hT[128][64] 16KB + adj[64][64] 16KB + c 256B,
// uniform 9 gll/wave; dbuf; steady-state s_waitcnt vmcnt(9) + RAW s_barrier
// (no drain-to-0 in loop). NO plain global loads in the loop -> vmcnt
// counting is sound (R6-proven regime; R9/R10 mixed-load class excluded).
// XOR swizzle phys = logical ^ ((row&7)<<4) on gll sources + reads.
template<int JSPLIT, bool PARTIAL>
__global__ __launch_bounds__(256, 2) void k2_attn(
        const int* __restrict__ adj, const short* __restrict__ hT,
        const float* __restrict__ s1g, const float* __restrict__ s2g,
        float* __restrict__ pvp, float* __restrict__ zp,
        float* __restrict__ out) {
    constexpr int JW = NN / JSPLIT;
    constexpr int NSTEP = JW / 64;
    constexpr int BUFB = 33792;            // hT 16K | adj 16K | c 1K
    __shared__ __align__(16) char lds_c[2 * BUFB + 512];

    const int tid = threadIdx.x;
    const int w = tid >> 6;
    const int l = tid & 63;
    const int quad = l >> 4;
    const int fr = l & 15;
    const int rh = w >> 1;
    const int wj = w & 1;
    const int rb = blockIdx.x / JSPLIT;
    const int jb = blockIdx.x % JSPLIT;
    const int r64 = rb * 64;
    const int jbb = jb * JW;

    const float S0 = s1g[r64 + rh * 32 + fr];        // m-tile 0 rows
    const float S1 = s1g[r64 + rh * 32 + 16 + fr];   // m-tile 1 rows

    // ---- pre-swizzled gll sources (linear LDS dest) ----
    const char* hsrc[4];
    const char* asrc[4];
    {
        const char* hbase = (const char*)hT;
        const char* abase = (const char*)adj;
#pragma unroll
        for (int p = 0; p < 4; ++p) {
            const int off = w * 4096 + p * 1024 + l * 16;
            {   // hT region: 128B per feature row
                const int row = off >> 7;
                const int colb = off & 127;
                hsrc[p] = hbase + (size_t)row * (NN * 2) + (size_t)jbb * 2
                        + (colb ^ ((row & 7) << 4));
            }
            {   // adj region: 256B per adj row (64 cols x 4B)
                const int row = off >> 8;
                const int colb = off & 255;
                asrc[p] = abase + (size_t)(r64 + row) * (NN * 4) + (size_t)jbb * 4
                        + (colb ^ ((row & 7) << 4));
            }
        }
    }
    const char* csrc = (const char*)s2g + (size_t)jbb * 4 + l * 16;

    auto STAGE = [&](int jt, int buf) {
        jt = (jt < NSTEP) ? jt : NSTEP - 1;           // tail clamp (junk, uniform count)
        char* hd = lds_c + buf * BUFB + w * 4096;
        char* ad = lds_c + buf * BUFB + 16384 + w * 4096;
        char* cd = lds_c + buf * BUFB + 32768;
        const size_t hof = (size_t)jt * 128;
        const size_t aof = (size_t)jt * 256;
#pragma unroll
        for (int p = 0; p < 4; ++p) gll16(hsrc[p] + hof, hd + p * 1024);
#pragma unroll
        for (int p = 0; p < 4; ++p) gll16(asrc[p] + aof, ad + p * 1024);
        gll16(csrc + aof, cd);                        // benign 4-wave WAW
    };

    f32x4 acc[2][8];
#pragma unroll
    for (int m = 0; m < 2; ++m)
#pragma unroll
        for (int t = 0; t < 8; ++t) acc[m][t] = zero4();
    float zacc0 = 0.f, zacc1 = 0.f;

    // prologue: 2 tiles in flight (18 gll/wave; S-loads older, drained below)
    STAGE(0, 0); STAGE(1, 1);

    const int ar0 = rh * 32 + fr;
    const int ar1 = rh * 32 + 16 + fr;
    const unsigned aswz = (unsigned)((ar0 & 7) << 4);   // (ar1&7)==(ar0&7)
    const unsigned a0 = (unsigned)(ar0 * 256 + wj * 128 + quad * 32);
    const unsigned a1 = (unsigned)(ar1 * 256 + wj * 128 + quad * 32);

    for (int t = 0; t < NSTEP; ++t) {
        const int cur = t & 1;
        // stage(t) ready once only stage(t+1)'s 9 gll remain outstanding
        asm volatile("s_waitcnt vmcnt(9)" ::: "memory");
        __builtin_amdgcn_s_barrier();
        __builtin_amdgcn_sched_barrier(0);

        const char* hb = lds_c + cur * BUFB;
        const char* ab = lds_c + cur * BUFB + 16384;
        const float* cb = (const float*)(lds_c + cur * BUFB + 32768);

        const int4v g00 = *(const int4v*)(ab + (a0 ^ aswz));
        const int4v g01 = *(const int4v*)(ab + ((a0 + 16) ^ aswz));
        const int4v g10 = *(const int4v*)(ab + (a1 ^ aswz));
        const int4v g11 = *(const int4v*)(ab + ((a1 + 16) ^ aswz));
        const f32x4 c0 = *(const f32x4*)((const char*)cb + wj * 128 + quad * 32);
        const f32x4 c1 = *(const f32x4*)((const char*)cb + wj * 128 + quad * 32 + 16);

        short8 pa0, pa1;
        {
            float zs0 = 0.f, zs1 = 0.f;
#pragma unroll
            for (int e = 0; e < 8; ++e) {
                const float cv = (e < 4) ? c0[e] : c1[e - 4];
                const int gv0 = (e < 4) ? g00[e] : g01[e - 4];
                const int gv1 = (e < 4) ? g10[e] : g11[e - 4];
                const float u0 = S0 + cv;
                const float u1 = S1 + cv;
                const float t0 = fmaxf(u0, 0.2f * u0);   // lrelu in log2 space
                const float t1 = fmaxf(u1, 0.2f * u1);
                const float p0 = (gv0 > 0) ? exp2f(t0) : 0.f;
                const float p1 = (gv1 > 0) ? exp2f(t1) : 0.f;
                zs0 += p0; zs1 += p1;
                pa0[e] = f2bf(p0);
                pa1[e] = f2bf(p1);
            }
            zacc0 += zs0; zacc1 += zs1;
        }

#pragma unroll
        for (int t8 = 0; t8 < 8; ++t8) {
            const int hrow = t8 * 16 + fr;
            const short8 bv = *(const short8*)(
                hb + ((unsigned)(hrow * 128 + wj * 64 + quad * 16) ^ ((hrow & 7) << 4)));
            acc[0][t8] = __builtin_amdgcn_mfma_f32_16x16x32_bf16(pa0, bv, acc[0][t8], 0, 0, 0);
            acc[1][t8] = __builtin_amdgcn_mfma_f32_16x16x32_bf16(pa1, bv, acc[1][t8], 0, 0, 0);
        }

        __builtin_amdgcn_sched_barrier(0);
        __builtin_amdgcn_s_barrier();                 // all reads of buf cur done
        STAGE(t + 2, cur);                            // refill freed buffer
    }

    asm volatile("s_waitcnt vmcnt(0)" ::: "memory");  // drain junk tail stages
    __syncthreads();

    // ---- epilogue: z + acc reduction over wj (red aliases staging LDS) ----
    zacc0 += __shfl_xor(zacc0, 16, 64);
    zacc0 += __shfl_xor(zacc0, 32, 64);
    zacc1 += __shfl_xor(zacc1, 16, 64);
    zacc1 += __shfl_xor(zacc1, 32, 64);
    float* zb = (float*)(lds_c + 2 * BUFB);           // 128 floats
    if (l < 16) {
        zb[w * 32 + l] = zacc0;
        zb[w * 32 + 16 + l] = zacc1;
    }

    float* red = (float*)lds_c;                       // 2 regions x 16KB
    if (wj == 1) {
#pragma unroll
        for (int m = 0; m < 2; ++m)
#pragma unroll
            for (int t8 = 0; t8 < 8; ++t8)
                *(f32x4*)(red + rh * 4096 + (m * 8 + t8) * 256 + l * 4) = acc[m][t8];
    }
    __syncthreads();

    if (wj == 0) {
#pragma unroll
        for (int m = 0; m < 2; ++m)
#pragma unroll
            for (int t8 = 0; t8 < 8; ++t8)
                acc[m][t8] += *(const f32x4*)(red + rh * 4096 + (m * 8 + t8) * 256 + l * 4);
#pragma unroll
        for (int m = 0; m < 2; ++m) {
#pragma unroll
            for (int r = 0; r < 4; ++r) {
                const int rr = m * 16 + quad * 4 + r;            // row within wave's 32
                const float z = zb[(rh * 2 + 0) * 32 + rr] + zb[(rh * 2 + 1) * 32 + rr];
                const int grow = r64 + rh * 32 + rr;
                if (PARTIAL) {
                    if (fr == 0) zp[(size_t)jb * NN + grow] = z;
                    float* orow = pvp + ((size_t)jb * NN + grow) * 128;
#pragma unroll
                    for (int t8 = 0; t8 < 8; ++t8) orow[t8 * 16 + fr] = acc[m][t8][r];
                } else {
                    const float inv = 1.0f / z;
                    float* orow = out + (size_t)grow * 128;
#pragma unroll
                    for (int t8 = 0; t8 < 8; ++t8) {
                        float v = acc[m][t8][r] * inv;
                        orow[t8 * 16 + fr] = (v > 0.f) ? v : expm1f(v);
                    }
                }
            }
        }
    }
}

// ---------- K3: sum partials, divide by Z, ELU ----------
__global__ __launch_bounds__(256) void k3_fin(
        const float* __restrict__ pvp, const float* __restrict__ zp,
        float* __restrict__ out, int jsplit) {
    const int idx = blockIdx.x * 256 + threadIdx.x;
    const int row = idx >> 5;
    const int c = (idx & 31) << 2;
    f32x4 s = zero4();
    float z = 0.f;
    for (int p = 0; p < jsplit; ++p) {
        s += *(const f32x4*)(pvp + ((size_t)p * NN + row) * 128 + c);
        z += zp[(size_t)p * NN + row];
    }
    const float inv = 1.0f / z;
    f32x4 o;
#pragma unroll
    for (int e = 0; e < 4; ++e) {
        float v = s[e] * inv;
        o[e] = (v > 0.f) ? v : expm1f(v);
    }
    *(f32x4*)(out + (size_t)row * 128 + c) = o;
}

extern "C" void kernel_launch(void* const* d_in, const int* in_sizes, int n_in,
                              void* d_out, int out_size, void* d_ws, size_t ws_size,
                              hipStream_t stream) {
    const float* x   = (const float*)d_in[0];   // 8192 x 256
    const float* W   = (const float*)d_in[1];   // 256 x 128
    const float* a   = (const float*)d_in[2];   // 256
    const int*   adj = (const int*)d_in[3];     // 8192 x 8192
    float* out = (float*)d_out;                 // 8192 x 128

    char* ws = (char*)d_ws;
    const size_t MB = 1024 * 1024;
    short* hT    = (short*)ws;                        // 2 MB
    float* s1L2E = (float*)(ws + 2 * MB);             // 32 KB
    float* s2L2E = (float*)(ws + 2 * MB + 32768);     // 32 KB
    short* WT    = (short*)(ws + 2 * MB + 65536);     // 64 KB
    const size_t base = 2 * MB + 131072;

    auto need = [&](size_t js) {
        return base + js * ((size_t)NN * 128 * 4) + js * ((size_t)NN * 4);
    };
    int jsplit;
    if (ws_size >= need(4)) jsplit = 4;
    else if (ws_size >= need(2)) jsplit = 2;
    else if (ws_size >= need(1)) jsplit = 1;
    else jsplit = 0;

    float* pvp = (float*)(ws + base);
    float* zp  = (float*)(ws + base + (size_t)(jsplit > 0 ? jsplit : 1) * NN * 128 * 4);

    k0_wt<<<128, 256, 0, stream>>>(W, WT);
    k1_h<<<256, 128, 0, stream>>>(x, WT, a, hT, s1L2E, s2L2E);

    if (jsplit == 4) {
        k2_attn<4, true><<<512, 256, 0, stream>>>(adj, hT, s1L2E, s2L2E, pvp, zp, nullptr);
        k3_fin<<<1024, 256, 0, stream>>>(pvp, zp, out, 4);
    } else if (jsplit == 2) {
        k2_attn<2, true><<<256, 256, 0, stream>>>(adj, hT, s1L2E, s2L2E, pvp, zp, nullptr);
        k3_fin<<<1024, 256, 0, stream>>>(pvp, zp, out, 2);
    } else if (jsplit == 1) {
        k2_attn<1, true><<<128, 256, 0, stream>>>(adj, hT, s1L2E, s2L2E, pvp, zp, nullptr);
        k3_fin<<<1024, 256, 0, stream>>>(pvp, zp, out, 1);
    } else {
        k2_attn<1, false><<<128, 256, 0, stream>>>(adj, hT, s1L2E, s2L2E, nullptr, nullptr, out);
    }
}